// Round 18
// baseline (345.671 us; speedup 1.0000x reference)
//
#include <hip/hip_runtime.h>
#include <hip/hip_bf16.h>
#include <stdint.h>

// ---------------------------------------------------------------------------
// TransformerLayer on MI355X (gfx950).
// bf16 MFMA GEMMs (128x128, 80B-pad LDS, 2-buffer loop, 4 blocks/CU; FF2
// K-split 2-way in one dispatch -> 3 blocks/CU), flash attn (R14-exact).
// ---------------------------------------------------------------------------

typedef __attribute__((ext_vector_type(8))) short bf16x8;   // 8 bf16 in 4 VGPRs
typedef __attribute__((ext_vector_type(4))) short bf16x4;   // 4 bf16 in 2 VGPRs
typedef __attribute__((ext_vector_type(4))) float f32x4;    // MFMA accumulator

#define MFMA_BF16(a, b, c) __builtin_amdgcn_mfma_f32_16x16x32_bf16((a), (b), (c), 0, 0, 0)

// raw v_exp_f32 (exp2) -- NOT exp2f(): OCML wrapper adds ~10 VALU fixup ops.
#define EXP2R(x) __builtin_amdgcn_exp2f(x)

__device__ __forceinline__ short f2bs(float f) {
  return __builtin_bit_cast(short, __float2bfloat16(f));
}
__device__ __forceinline__ float bs2f(short s) {
  union { unsigned u; float f; } v;
  v.u = ((unsigned)(unsigned short)s) << 16;
  return v.f;
}

// async global->LDS, 16B per lane; LDS dest wave-uniform base + lane*16.
__device__ __forceinline__ void gload16(const void* g, void* l) {
  __builtin_amdgcn_global_load_lds(
      (const __attribute__((address_space(1))) unsigned int*)g,
      (__attribute__((address_space(3))) unsigned int*)l, 16, 0, 0);
}

// LDS byte offset of a __shared__ pointer (low 32 bits of generic address).
__device__ __forceinline__ unsigned ldsoff(const void* p) {
  return (unsigned)(uintptr_t)p;
}

// hardware transpose read: lane reads 4 bf16 at addr + j*32B (j=0..3)
#define TRD(dst, base, off) \
  asm volatile("ds_read_b64_tr_b16 %0, %1 offset:" #off : "=v"(dst) : "v"(base) : "memory")

// ---------------------------------------------------------------------------
// weight transpose + fp32->bf16 cast:  W[K][N] -> Wt[N][K]
// ---------------------------------------------------------------------------
__global__ __launch_bounds__(256) void transpose_cast(const float* __restrict__ W,
                                                      short* __restrict__ Wt,
                                                      int K, int N) {
  __shared__ float tile[32][33];
  const int n0 = blockIdx.x * 32, k0 = blockIdx.y * 32;
  const int tx = threadIdx.x & 31, ty = threadIdx.x >> 5;  // 32 x 8
#pragma unroll
  for (int i = 0; i < 4; ++i)
    tile[ty + i * 8][tx] = W[(size_t)(k0 + ty + i * 8) * N + n0 + tx];
  __syncthreads();
#pragma unroll
  for (int i = 0; i < 4; ++i)
    Wt[(size_t)(n0 + ty + i * 8) * K + k0 + tx] = f2bs(tile[tx][ty + i * 8]);
}

__global__ __launch_bounds__(256) void cast_bf16(const float* __restrict__ x,
                                                 short* __restrict__ y, int n4) {
  const int i = blockIdx.x * 256 + threadIdx.x;
  if (i < n4) {
    const float4 v = *(const float4*)(x + (size_t)i * 4);
    short4 o;
    o.x = f2bs(v.x); o.y = f2bs(v.y); o.z = f2bs(v.z); o.w = f2bs(v.w);
    *(short4*)(y + (size_t)i * 4) = o;
  }
}

// ---------------------------------------------------------------------------
// GEMM:  C[M,N] = A[M,Kstride](bf16) * Bt[N,Kstride]^T(bf16) + bias.
// This block iterates K elements starting at blockIdx.z * K (K-split support:
// z=0 writes outp (+bias), z=1 writes outp2 (no bias); caller sums).
// 128x128 tile, BK=32, 256 threads (2x2 waves, 4x4 frags), 80B-padded LDS
// rows (2-way-free ds_read), 2-buffer full-drain loop (R17-measured best).
// EPI: 0 = scatter to qkv[3][B][H][S][96]; 1 = bf16 out; 2 = GELU -> bf16.
// ---------------------------------------------------------------------------
template <int EPI>
__global__ __launch_bounds__(256) void gemm_bt(const short* __restrict__ A,
                                               const short* __restrict__ Bt,
                                               const float* __restrict__ bias,
                                               void* __restrict__ outp,
                                               void* __restrict__ outp2,
                                               int N, int K, int kstride) {
  // one buffer = 20480B: [A rows 0-127][B rows 0-127], row stride 80B
  __shared__ __align__(16) short ls[2][10240];
  const int tid = threadIdx.x;
  const int lane = tid & 63, w = tid >> 6;
  const int lo = lane & 15, hi = lane >> 4;
  const int wr = w >> 1, wc = w & 1;
  const int ks = blockIdx.z;
  const size_t aoff = (size_t)ks * K;

  // XCD-aware swizzle over (x,y) (bijective: all grids have x*y % 8 == 0)
  const unsigned gdx = gridDim.x;
  const unsigned nwg = gdx * gridDim.y;
  unsigned lin = blockIdx.y * gdx + blockIdx.x;
  if ((nwg & 7u) == 0u) lin = (lin & 7u) * (nwg >> 3) + (lin >> 3);
  const unsigned by = lin / gdx, bx = lin - by * gdx;
  const int m0 = by * 128, n0 = bx * 128;

  f32x4 acc[4][4] = {};

  // per-thread source row pointers for the 5 staging sweeps (K-invariant)
  const short* rowsrc[5];
#pragma unroll
  for (int s = 0; s < 5; ++s) {
    const int u = s * 256 + tid;          // unit index, 0..1279
    const int chunk = u / 320;            // 0,1 = A rows 0-63/64-127; 2,3 = B
    const int uin = u - chunk * 320;
    const int r = uin / 5, ui = uin - r * 5;
    const int koff = (ui < 4) ? ui * 8 : 0;   // unit 4 = pad (dup, never read)
    rowsrc[s] = (chunk < 2 ? A + (size_t)(m0 + chunk * 64 + r) * kstride
                           : Bt + (size_t)(n0 + (chunk - 2) * 64 + r) * kstride)
                + aoff + koff;
  }

  auto stage = [&](int kt, int buf) {
    char* base = (char*)ls[buf] + w * 1024;
#pragma unroll
    for (int s = 0; s < 5; ++s)
      gload16(rowsrc[s] + kt, base + s * 4096);
  };

  const int nk = K >> 5;
  stage(0, 0);
  for (int t = 0; t < nk; ++t) {
    const int cur = t & 1;
    __syncthreads();                     // drains stage(t) + prev reads
    if (t + 1 < nk) stage((t + 1) << 5, cur ^ 1);
    bf16x8 af[4], bfr[4];
    const char* lbase = (const char*)ls[cur];
#pragma unroll
    for (int i = 0; i < 4; ++i) {
      af[i]  = *(const bf16x8*)(lbase + (wr * 64 + i * 16 + lo) * 80 + hi * 16);
      bfr[i] = *(const bf16x8*)(lbase + 10240 + (wc * 64 + i * 16 + lo) * 80 + hi * 16);
    }
#pragma unroll
    for (int mi = 0; mi < 4; ++mi)
#pragma unroll
      for (int ni = 0; ni < 4; ++ni)
        acc[mi][ni] = MFMA_BF16(af[mi], bfr[ni], acc[mi][ni]);
  }

  void* op = ks ? outp2 : outp;
  const int rb = m0 + wr * 64, cb = n0 + wc * 64;
#pragma unroll
  for (int ni = 0; ni < 4; ++ni) {
    const int col = cb + ni * 16 + lo;
    const float bc = ks ? 0.f : bias[col];
#pragma unroll
    for (int mi = 0; mi < 4; ++mi) {
#pragma unroll
      for (int r = 0; r < 4; ++r) {
        const int row = rb + mi * 16 + hi * 4 + r;
        const float v = acc[mi][ni][r] + bc;
        if constexpr (EPI == 0) {
          const int which = col / 768, rem = col - which * 768;
          const int hh = rem / 96, d = rem - hh * 96;
          const int bb = row >> 12, ss = row & 4095;
          ((short*)op)[((size_t)((which * 2 + bb) * 8 + hh) * 4096 + ss) * 96 + d] = f2bs(v);
        } else if constexpr (EPI == 1) {
          ((short*)op)[(size_t)row * N + col] = f2bs(v);
        } else {
          const float ge = 0.5f * v * (1.f + erff(v * 0.70710678118654752f));
          ((short*)op)[(size_t)row * N + col] = f2bs(ge);
        }
      }
    }
  }
}

// ---------------------------------------------------------------------------
// flash attention: qkv[3][B][H][S][96] bf16 -> out[B][S][768] bf16
// block = (b, h, 128 q-rows); 4 waves x 32 q-rows; KV tiles of 64, dbuf.
// [R14-exact, measured 132.6us] XCD remap: (qt = lin>>4, hb = lin&15) ->
// head-pair per XCD, FETCH 104->18.5MB.
// ---------------------------------------------------------------------------
__global__ __launch_bounds__(256, 2) void attn_fwd(const short* __restrict__ qkv,
                                                   short* __restrict__ out) {
  constexpr int SEQ = 4096;
  constexpr int NT = SEQ / 64;
  constexpr float SCALE2 = 0.10206207261596575f * 1.44269504088896f;  // /sqrt(96)*log2e
  constexpr float THR2 = 11.5415603f;  // 8 nats in log2 units
  const unsigned linear = blockIdx.x + 32u * (blockIdx.y + 8u * blockIdx.z);
  const int qt = linear >> 4;
  const int hb = linear & 15;
  const int h = hb & 7, b = hb >> 3;
  const int tid = threadIdx.x;
  const int lane = tid & 63, w = tid >> 6;
  const int lo = lane & 15, hi = lane >> 4;

  const size_t headsz = (size_t)SEQ * 96;
  const short* Qh = qkv + (size_t)((0 * 2 + b) * 8 + h) * headsz;
  const short* Kh = qkv + (size_t)((1 * 2 + b) * 8 + h) * headsz;
  const short* Vh = qkv + (size_t)((2 * 2 + b) * 8 + h) * headsz;

  __shared__ __align__(16) short k_lds[2][6144];   // [64][96] row-major
  __shared__ __align__(16) short v_lds[2][6144];   // subtiled for tr-read
  __shared__ __align__(16) short p_lds[4][2048];   // per-wave P^T subtiled

  int voff[3];
#pragma unroll
  for (int t = 0; t < 3; ++t) {
    const int c = t * 256 + tid;
    const int kq = c / 48, rem = c - kq * 48;
    const int dhi = rem >> 3, rem2 = rem & 7;
    voff[t] = (kq * 4 + (rem2 >> 1)) * 96 + dhi * 16 + (rem2 & 1) * 8;
  }

  const int qbase = qt * 128 + w * 32;
  bf16x8 qf[2][3];
#pragma unroll
  for (int f = 0; f < 2; ++f)
#pragma unroll
    for (int dk = 0; dk < 3; ++dk) {
      bf16x8 v = *(const bf16x8*)(Qh + (size_t)(qbase + f * 16 + lo) * 96 + dk * 32 + hi * 8);
#pragma unroll
      for (int i = 0; i < 8; ++i) v[i] = f2bs(bs2f(v[i]) * SCALE2);
      qf[f][dk] = v;
    }

  f32x4 o[2][6] = {};
  float mrow[2][4] = {};   // deferred max (log2 units), init 0
  float lpart[2][4] = {};  // per-lane partial row sums
  bool escaped = false;

  auto stage = [&](int t_next, int buf) {
    const short* Kt = Kh + (size_t)t_next * 6144;
    const short* Vt = Vh + (size_t)t_next * 6144;
    char* kd = (char*)k_lds[buf] + w * 1024;
    char* vd = (char*)v_lds[buf] + w * 1024;
#pragma unroll
    for (int t = 0; t < 3; ++t) {
      gload16((const char*)Kt + (t * 256 + tid) * 16, kd + t * 4096);
      gload16(Vt + voff[t], vd + t * 4096);
    }
  };

  stage(0, 0);

  for (int kt = 0; kt < NT; ++kt) {
    const int cur = kt & 1;
    __syncthreads();
    if (kt + 1 < NT) stage(kt + 1, cur ^ 1);

    // ---- QK^T (scores in log2 units) ----
    f32x4 s[2][4] = {};
    const short* kb = k_lds[cur];
#pragma unroll
    for (int dk = 0; dk < 3; ++dk)
#pragma unroll
      for (int c = 0; c < 4; ++c) {
        const bf16x8 kf = *(const bf16x8*)(kb + (c * 16 + lo) * 96 + dk * 32 + hi * 8);
#pragma unroll
        for (int f = 0; f < 2; ++f)
          s[f][c] = MFMA_BF16(qf[f][dk], kf, s[f][c]);
      }

    // ---- softmax (defer-max, log2 domain) ----
    float tm = s[0][0][0];
#pragma unroll
    for (int f = 0; f < 2; ++f)
#pragma unroll
      for (int c = 0; c < 4; ++c)
#pragma unroll
        for (int r = 0; r < 4; ++r) tm = fmaxf(tm, s[f][c][r]);

    if (!__all(tm <= THR2)) {
      escaped = true;
#pragma unroll
      for (int f = 0; f < 2; ++f)
#pragma unroll
        for (int r = 0; r < 4; ++r) {
          float rm = fmaxf(fmaxf(s[f][0][r], s[f][1][r]), fmaxf(s[f][2][r], s[f][3][r]));
          rm = fmaxf(rm, __shfl_xor(rm, 1));
          rm = fmaxf(rm, __shfl_xor(rm, 2));
          rm = fmaxf(rm, __shfl_xor(rm, 4));
          rm = fmaxf(rm, __shfl_xor(rm, 8));
          const float mn = fmaxf(mrow[f][r], rm);
          const float al = EXP2R(mrow[f][r] - mn);
          mrow[f][r] = mn;
          lpart[f][r] *= al;
#pragma unroll
          for (int n = 0; n < 6; ++n) o[f][n][r] *= al;
        }
    }
    if (escaped) {
#pragma unroll
      for (int f = 0; f < 2; ++f)
#pragma unroll
        for (int c = 0; c < 4; ++c)
#pragma unroll
        for (int r = 0; r < 4; ++r) s[f][c][r] = EXP2R(s[f][c][r] - mrow[f][r]);
    } else {
#pragma unroll
      for (int f = 0; f < 2; ++f)
#pragma unroll
        for (int c = 0; c < 4; ++c)
#pragma unroll
        for (int r = 0; r < 4; ++r) s[f][c][r] = EXP2R(s[f][c][r]);
    }

    // ---- lpart accumulate + P^T subtiled store ----
    short* pw = p_lds[w];
#pragma unroll
    for (int f = 0; f < 2; ++f)
#pragma unroll
      for (int c = 0; c < 4; ++c) {
#pragma unroll
        for (int r = 0; r < 4; ++r) lpart[f][r] += s[f][c][r];
        short4 pk;
        pk.x = f2bs(s[f][c][0]);
        pk.y = f2bs(s[f][c][1]);
        pk.z = f2bs(s[f][c][2]);
        pk.w = f2bs(s[f][c][3]);
        *(short4*)(pw + (c * 4 + (lo >> 2)) * 128 + f * 64 + (lo & 3) * 16 + hi * 4) = pk;
      }

    // ---- PV: tr-read V (B-op) and P^T (A-op), MFMA ----
    const unsigned vb = ldsoff(v_lds[cur]) + (unsigned)(hi * 1536 + lo * 2);
    const unsigned pb = ldsoff(p_lds[w]) + (unsigned)(hi * 512 + lo * 2);

    {  // kk = 0
      bf16x4 va[6], vbh[6], pa0[2], pa1[2];
      TRD(va[0], vb, 0);     TRD(vbh[0], vb, 768);
      TRD(va[1], vb, 128);   TRD(vbh[1], vb, 896);
      TRD(va[2], vb, 256);   TRD(vbh[2], vb, 1024);
      TRD(va[3], vb, 384);   TRD(vbh[3], vb, 1152);
      TRD(va[4], vb, 512);   TRD(vbh[4], vb, 1280);
      TRD(va[5], vb, 640);   TRD(vbh[5], vb, 1408);
      TRD(pa0[0], pb, 0);    TRD(pa1[0], pb, 256);
      TRD(pa0[1], pb, 128);  TRD(pa1[1], pb, 384);
      asm volatile("s_waitcnt lgkmcnt(0)" ::: "memory");
      __builtin_amdgcn_sched_barrier(0);
      __builtin_amdgcn_s_setprio(1);
#pragma unroll
      for (int f = 0; f < 2; ++f) {
        const bf16x8 pf = __builtin_shufflevector(pa0[f], pa1[f], 0, 1, 2, 3, 4, 5, 6, 7);
#pragma unroll
        for (int n = 0; n < 6; ++n) {
          const bf16x8 vf = __builtin_shufflevector(va[n], vbh[n], 0, 1, 2, 3, 4, 5, 6, 7);
          o[f][n] = MFMA_BF16(pf, vf, o[f][n]);
        }
      }
      __builtin_amdgcn_s_setprio(0);
    }
    {  // kk = 1 (V +6144 bytes, P +2048 bytes)
      bf16x4 va[6], vbh[6], pa0[2], pa1[2];
      TRD(va[0], vb, 6144);  TRD(vbh[0], vb, 6912);
      TRD(va[1], vb, 6272);  TRD(vbh[1], vb, 7040);
      TRD(va[2], vb, 6400);  TRD(vbh[2], vb, 7168);
      TRD(va[3], vb, 6528);  TRD(vbh[3], vb, 7296);
      TRD(va[4], vb, 6656);  TRD(vbh[4], vb, 7424);
      TRD(va[5], vb, 6784);  TRD(vbh[5], vb, 7552);
      TRD(pa0[0], pb, 2048); TRD(pa1[0], pb, 2304);
      TRD(pa0[1], pb, 2176); TRD(pa1[1], pb, 2432);
      asm volatile("s_waitcnt lgkmcnt(0)" ::: "memory");
      __builtin_amdgcn_sched_barrier(0);
      __builtin_amdgcn_s_setprio(1);
#pragma unroll
      for (int f = 0; f < 2; ++f) {
        const bf16x8 pf = __builtin_shufflevector(pa0[f], pa1[f], 0, 1, 2, 3, 4, 5, 6, 7);
#pragma unroll
        for (int n = 0; n < 6; ++n) {
          const bf16x8 vf = __builtin_shufflevector(va[n], vbh[n], 0, 1, 2, 3, 4, 5, 6, 7);
          o[f][n] = MFMA_BF16(pf, vf, o[f][n]);
        }
      }
      __builtin_amdgcn_s_setprio(0);
    }
  }

  // ---- epilogue ----
  float inv[2][4];
#pragma unroll
  for (int f = 0; f < 2; ++f)
#pragma unroll
    for (int r = 0; r < 4; ++r) {
      float l = lpart[f][r];
      l += __shfl_xor(l, 1);
      l += __shfl_xor(l, 2);
      l += __shfl_xor(l, 4);
      l += __shfl_xor(l, 8);
      inv[f][r] = 1.f / l;
    }
#pragma unroll
  for (int f = 0; f < 2; ++f)
#pragma unroll
    for (int n = 0; n < 6; ++n)
#pragma unroll
      for (int r = 0; r < 4; ++r) {
        const int q = qbase + f * 16 + hi * 4 + r;
        out[((size_t)(b * SEQ + q)) * 768 + h * 96 + n * 16 + lo] = f2bs(o[f][n][r] * inv[f][r]);
      }
}

// ---------------------------------------------------------------------------
// LN(a + r [+ r2]) with bf16 residuals.  MODE 0 (LN1): a fp32, one residual,
// write bf16.  MODE 1 (LN2): a bf16, TWO residuals (K-split FF2 halves),
// write fp32.
// ---------------------------------------------------------------------------
template <int MODE>
__global__ __launch_bounds__(192) void ln_residual(const void* __restrict__ xa_,
                                                   const short* __restrict__ xr,
                                                   const short* __restrict__ xr2,
                                                   const float* __restrict__ g,
                                                   const float* __restrict__ be,
                                                   float* __restrict__ outf,
                                                   short* __restrict__ outb) {
  const int row = blockIdx.x, t = threadIdx.x;
  const size_t base = (size_t)row * 768 + t * 4;
  float a0, a1, a2, a3;
  if constexpr (MODE == 0) {
    const float4 a = *(const float4*)((const float*)xa_ + base);
    a0 = a.x; a1 = a.y; a2 = a.z; a3 = a.w;
  } else {
    const short4 a = *(const short4*)((const short*)xa_ + base);
    a0 = bs2f(a.x); a1 = bs2f(a.y); a2 = bs2f(a.z); a3 = bs2f(a.w);
  }
  const short4 bl = *(const short4*)(xr + base);
  float v0 = a0 + bs2f(bl.x), v1 = a1 + bs2f(bl.y);
  float v2 = a2 + bs2f(bl.z), v3 = a3 + bs2f(bl.w);
  if constexpr (MODE == 1) {
    const short4 b2 = *(const short4*)(xr2 + base);
    v0 += bs2f(b2.x); v1 += bs2f(b2.y); v2 += bs2f(b2.z); v3 += bs2f(b2.w);
  }
  float s = v0 + v1 + v2 + v3;
  float q = v0 * v0 + v1 * v1 + v2 * v2 + v3 * v3;
#pragma unroll
  for (int m = 32; m; m >>= 1) {
    s += __shfl_xor(s, m);
    q += __shfl_xor(q, m);
  }
  __shared__ float red[2][3];
  const int w = t >> 6;
  if ((t & 63) == 0) { red[0][w] = s; red[1][w] = q; }
  __syncthreads();
  s = red[0][0] + red[0][1] + red[0][2];
  q = red[1][0] + red[1][1] + red[1][2];
  const float mu = s * (1.f / 768.f);
  const float var = q * (1.f / 768.f) - mu * mu;
  const float rstd = rsqrtf(var + 1e-5f);
  const int c = t * 4;
  const float4 gg = *(const float4*)(g + c);
  const float4 bb = *(const float4*)(be + c);
  const float y0 = (v0 - mu) * rstd * gg.x + bb.x;
  const float y1 = (v1 - mu) * rstd * gg.y + bb.y;
  const float y2 = (v2 - mu) * rstd * gg.z + bb.z;
  const float y3 = (v3 - mu) * rstd * gg.w + bb.w;
  if constexpr (MODE == 0) {
    short4 ob;
    ob.x = f2bs(y0); ob.y = f2bs(y1); ob.z = f2bs(y2); ob.w = f2bs(y3);
    *(short4*)(outb + base) = ob;
  } else {
    float4 ov = {y0, y1, y2, y3};
    *(float4*)(outf + base) = ov;
  }
}

// ---------------------------------------------------------------------------
extern "C" void kernel_launch(void* const* d_in, const int* in_sizes, int n_in,
                              void* d_out, int out_size, void* d_ws, size_t ws_size,
                              hipStream_t stream) {
  const float* x     = (const float*)d_in[0];
  const float* w_qkv = (const float*)d_in[1];
  const float* b_qkv = (const float*)d_in[2];
  const float* w_out = (const float*)d_in[3];
  const float* b_out = (const float*)d_in[4];
  const float* w_ff1 = (const float*)d_in[5];
  const float* b_ff1 = (const float*)d_in[6];
  const float* w_ff2 = (const float*)d_in[7];
  const float* b_ff2 = (const float*)d_in[8];
  const float* g1  = (const float*)d_in[9];
  const float* be1 = (const float*)d_in[10];
  const float* g2  = (const float*)d_in[11];
  const float* be2 = (const float*)d_in[12];

  char* ws = (char*)d_ws;
  size_t off = 0;
  auto take = [&](size_t bytes) {
    char* p = ws + off;
    off += (bytes + 255) & ~(size_t)255;
    return p;
  };
  short* wqkv_t = (short*)take((size_t)2304 * 768 * 2);
  short* wout_t = (short*)take((size_t)768 * 768 * 2);
  short* wff1_t = (short*)take((size_t)3072 * 768 * 2);
  short* wff2_t = (short*)take((size_t)768 * 3072 * 2);
  short* xb     = (short*)take((size_t)8192 * 768 * 2);
  short* qkv    = (short*)take((size_t)3 * 2 * 8 * 4096 * 96 * 2);
  short* ao     = (short*)take((size_t)8192 * 768 * 2);
  short* x1b    = (short*)take((size_t)8192 * 768 * 2);
  short* ff2b   = (short*)take((size_t)8192 * 768 * 2);
  if (ws_size < off) return;

  short* proj = qkv;          // alias: qkv dead after attention (bf16)
  short* hbuf = xb;           // alias: xb+qkv region
  short* ff2a = ao;           // alias: ao region (bf16)

  cast_bf16<<<dim3(6144), dim3(256), 0, stream>>>(x, xb, 8192 * 768 / 4);
  transpose_cast<<<dim3(2304 / 32, 768 / 32), dim3(256), 0, stream>>>(w_qkv, wqkv_t, 768, 2304);
  transpose_cast<<<dim3(768 / 32, 768 / 32), dim3(256), 0, stream>>>(w_out, wout_t, 768, 768);
  transpose_cast<<<dim3(3072 / 32, 768 / 32), dim3(256), 0, stream>>>(w_ff1, wff1_t, 768, 3072);
  transpose_cast<<<dim3(768 / 32, 3072 / 32), dim3(256), 0, stream>>>(w_ff2, wff2_t, 3072, 768);

  gemm_bt<0><<<dim3(2304 / 128, 8192 / 128), dim3(256), 0, stream>>>(
      xb, wqkv_t, b_qkv, qkv, nullptr, 2304, 768, 768);

  attn_fwd<<<dim3(32, 8, 2), dim3(256), 0, stream>>>(qkv, ao);

  gemm_bt<1><<<dim3(768 / 128, 8192 / 128), dim3(256), 0, stream>>>(
      ao, wout_t, b_out, proj, nullptr, 768, 768, 768);

  ln_residual<0><<<dim3(8192), dim3(192), 0, stream>>>(x, proj, nullptr, g1, be1, nullptr, x1b);

  gemm_bt<2><<<dim3(3072 / 128, 8192 / 128), dim3(256), 0, stream>>>(
      x1b, wff1_t, b_ff1, hbuf, nullptr, 3072, 768, 768);

  // FF2 K-split: z=0 -> ff2a (K 0..1535, +bias), z=1 -> ff2b (K 1536..3071)
  gemm_bt<1><<<dim3(768 / 128, 8192 / 128, 2), dim3(256), 0, stream>>>(
      hbuf, wff2_t, b_ff2, ff2a, ff2b, 768, 1536, 3072);

  ln_residual<1><<<dim3(8192), dim3(192), 0, stream>>>(x1b, ff2a, ff2b, g2, be2, (float*)d_out, nullptr);
}

// Round 19
// 330.110 us; speedup vs baseline: 1.0471x; 1.0471x over previous
//
#include <hip/hip_runtime.h>
#include <hip/hip_bf16.h>
#include <stdint.h>

// ---------------------------------------------------------------------------
// TransformerLayer on MI355X (gfx950).
// bf16 MFMA GEMMs (128x128, 80B-pad LDS, 2-buffer R7 loop -> 4 blocks/CU),
// flash attn (R14-exact), tanh-form GELU via raw exp2 (R19).
// ---------------------------------------------------------------------------

typedef __attribute__((ext_vector_type(8))) short bf16x8;   // 8 bf16 in 4 VGPRs
typedef __attribute__((ext_vector_type(4))) short bf16x4;   // 4 bf16 in 2 VGPRs
typedef __attribute__((ext_vector_type(4))) float f32x4;    // MFMA accumulator

#define MFMA_BF16(a, b, c) __builtin_amdgcn_mfma_f32_16x16x32_bf16((a), (b), (c), 0, 0, 0)

// raw v_exp_f32 (exp2) -- NOT exp2f(): OCML wrapper adds ~10 VALU fixup ops.
#define EXP2R(x) __builtin_amdgcn_exp2f(x)

__device__ __forceinline__ short f2bs(float f) {
  return __builtin_bit_cast(short, __float2bfloat16(f));
}
__device__ __forceinline__ float bs2f(short s) {
  union { unsigned u; float f; } v;
  v.u = ((unsigned)(unsigned short)s) << 16;
  return v.f;
}

// tanh-form GELU, all-raw ops (~12 VALU vs OCML erf ~25): max |err| < 1e-3,
// absorbed by bf16 output rounding.  [R19]
__device__ __forceinline__ float gelu_fast(float v) {
  const float u = v * (0.79788456080286536f + 0.035677408136300125f * v * v);
  const float e = EXP2R(u * 2.8853900817779268f);   // e^(2u)
  const float th = (e - 1.f) * __builtin_amdgcn_rcpf(e + 1.f);
  return 0.5f * v * (1.f + th);
}

// async global->LDS, 16B per lane; LDS dest wave-uniform base + lane*16.
__device__ __forceinline__ void gload16(const void* g, void* l) {
  __builtin_amdgcn_global_load_lds(
      (const __attribute__((address_space(1))) unsigned int*)g,
      (__attribute__((address_space(3))) unsigned int*)l, 16, 0, 0);
}

// LDS byte offset of a __shared__ pointer (low 32 bits of generic address).
__device__ __forceinline__ unsigned ldsoff(const void* p) {
  return (unsigned)(uintptr_t)p;
}

// hardware transpose read: lane reads 4 bf16 at addr + j*32B (j=0..3)
#define TRD(dst, base, off) \
  asm volatile("ds_read_b64_tr_b16 %0, %1 offset:" #off : "=v"(dst) : "v"(base) : "memory")

// ---------------------------------------------------------------------------
// weight transpose + fp32->bf16 cast:  W[K][N] -> Wt[N][K]
// ---------------------------------------------------------------------------
__global__ __launch_bounds__(256) void transpose_cast(const float* __restrict__ W,
                                                      short* __restrict__ Wt,
                                                      int K, int N) {
  __shared__ float tile[32][33];
  const int n0 = blockIdx.x * 32, k0 = blockIdx.y * 32;
  const int tx = threadIdx.x & 31, ty = threadIdx.x >> 5;  // 32 x 8
#pragma unroll
  for (int i = 0; i < 4; ++i)
    tile[ty + i * 8][tx] = W[(size_t)(k0 + ty + i * 8) * N + n0 + tx];
  __syncthreads();
#pragma unroll
  for (int i = 0; i < 4; ++i)
    Wt[(size_t)(n0 + ty + i * 8) * K + k0 + tx] = f2bs(tile[tx][ty + i * 8]);
}

__global__ __launch_bounds__(256) void cast_bf16(const float* __restrict__ x,
                                                 short* __restrict__ y, int n4) {
  const int i = blockIdx.x * 256 + threadIdx.x;
  if (i < n4) {
    const float4 v = *(const float4*)(x + (size_t)i * 4);
    short4 o;
    o.x = f2bs(v.x); o.y = f2bs(v.y); o.z = f2bs(v.z); o.w = f2bs(v.w);
    *(short4*)(y + (size_t)i * 4) = o;
  }
}

// ---------------------------------------------------------------------------
// GEMM:  C[M,N] = A[M,K](bf16) * Bt[N,K]^T(bf16) + bias.  128x128 tile, BK=32,
// 256 threads (2x2 waves, 4x4 frags).
// 2-buffer (40KB) + full-drain syncthreads loop: 4 blocks/CU, with 80B-padded
// rows keeping ds_read at the 2-way floor.  [R17-measured best]
// EPI: 0 = scatter to qkv[3][B][H][S][96]; 1 = bf16 out; 2 = GELU -> bf16.
// ---------------------------------------------------------------------------
template <int EPI>
__global__ __launch_bounds__(256) void gemm_bt(const short* __restrict__ A,
                                               const short* __restrict__ Bt,
                                               const float* __restrict__ bias,
                                               void* __restrict__ outp,
                                               int N, int K) {
  // one buffer = 20480B: [A rows 0-127][B rows 0-127], row stride 80B
  __shared__ __align__(16) short ls[2][10240];
  const int tid = threadIdx.x;
  const int lane = tid & 63, w = tid >> 6;
  const int lo = lane & 15, hi = lane >> 4;
  const int wr = w >> 1, wc = w & 1;

  // XCD-aware swizzle (bijective: all grids have nwg % 8 == 0)
  const unsigned gdx = gridDim.x;
  const unsigned nwg = gdx * gridDim.y;
  unsigned lin = blockIdx.y * gdx + blockIdx.x;
  if ((nwg & 7u) == 0u) lin = (lin & 7u) * (nwg >> 3) + (lin >> 3);
  const unsigned by = lin / gdx, bx = lin - by * gdx;
  const int m0 = by * 128, n0 = bx * 128;

  f32x4 acc[4][4] = {};

  // per-thread source row pointers for the 5 staging sweeps (K-invariant)
  const short* rowsrc[5];
#pragma unroll
  for (int s = 0; s < 5; ++s) {
    const int u = s * 256 + tid;          // unit index, 0..1279
    const int chunk = u / 320;            // 0,1 = A rows 0-63/64-127; 2,3 = B
    const int uin = u - chunk * 320;
    const int r = uin / 5, ui = uin - r * 5;
    const int koff = (ui < 4) ? ui * 8 : 0;   // unit 4 = pad (dup, never read)
    rowsrc[s] = (chunk < 2 ? A + (size_t)(m0 + chunk * 64 + r) * K
                           : Bt + (size_t)(n0 + (chunk - 2) * 64 + r) * K) + koff;
  }

  auto stage = [&](int kt, int buf) {
    char* base = (char*)ls[buf] + w * 1024;
#pragma unroll
    for (int s = 0; s < 5; ++s)
      gload16(rowsrc[s] + kt, base + s * 4096);
  };

  const int nk = K >> 5;
  stage(0, 0);
  for (int t = 0; t < nk; ++t) {
    const int cur = t & 1;
    __syncthreads();                     // drains stage(t) + prev reads
    if (t + 1 < nk) stage((t + 1) << 5, cur ^ 1);
    bf16x8 af[4], bfr[4];
    const char* lbase = (const char*)ls[cur];
#pragma unroll
    for (int i = 0; i < 4; ++i) {
      af[i]  = *(const bf16x8*)(lbase + (wr * 64 + i * 16 + lo) * 80 + hi * 16);
      bfr[i] = *(const bf16x8*)(lbase + 10240 + (wc * 64 + i * 16 + lo) * 80 + hi * 16);
    }
#pragma unroll
    for (int mi = 0; mi < 4; ++mi)
#pragma unroll
      for (int ni = 0; ni < 4; ++ni)
        acc[mi][ni] = MFMA_BF16(af[mi], bfr[ni], acc[mi][ni]);
  }

  const int rb = m0 + wr * 64, cb = n0 + wc * 64;
#pragma unroll
  for (int ni = 0; ni < 4; ++ni) {
    const int col = cb + ni * 16 + lo;
    const float bc = bias[col];
#pragma unroll
    for (int mi = 0; mi < 4; ++mi) {
#pragma unroll
      for (int r = 0; r < 4; ++r) {
        const int row = rb + mi * 16 + hi * 4 + r;
        const float v = acc[mi][ni][r] + bc;
        if constexpr (EPI == 0) {
          const int which = col / 768, rem = col - which * 768;
          const int hh = rem / 96, d = rem - hh * 96;
          const int bb = row >> 12, ss = row & 4095;
          ((short*)outp)[((size_t)((which * 2 + bb) * 8 + hh) * 4096 + ss) * 96 + d] = f2bs(v);
        } else if constexpr (EPI == 1) {
          ((short*)outp)[(size_t)row * N + col] = f2bs(v);
        } else {
          ((short*)outp)[(size_t)row * N + col] = f2bs(gelu_fast(v));
        }
      }
    }
  }
}

// ---------------------------------------------------------------------------
// flash attention: qkv[3][B][H][S][96] bf16 -> out[B][S][768] bf16
// block = (b, h, 128 q-rows); 4 waves x 32 q-rows; KV tiles of 64, dbuf.
// [R14-exact, measured 132.6us] XCD remap: (qt = lin>>4, hb = lin&15) ->
// head-pair per XCD, FETCH 104->18.5MB.
// ---------------------------------------------------------------------------
__global__ __launch_bounds__(256, 2) void attn_fwd(const short* __restrict__ qkv,
                                                   short* __restrict__ out) {
  constexpr int SEQ = 4096;
  constexpr int NT = SEQ / 64;
  constexpr float SCALE2 = 0.10206207261596575f * 1.44269504088896f;  // /sqrt(96)*log2e
  constexpr float THR2 = 11.5415603f;  // 8 nats in log2 units
  const unsigned linear = blockIdx.x + 32u * (blockIdx.y + 8u * blockIdx.z);
  const int qt = linear >> 4;
  const int hb = linear & 15;
  const int h = hb & 7, b = hb >> 3;
  const int tid = threadIdx.x;
  const int lane = tid & 63, w = tid >> 6;
  const int lo = lane & 15, hi = lane >> 4;

  const size_t headsz = (size_t)SEQ * 96;
  const short* Qh = qkv + (size_t)((0 * 2 + b) * 8 + h) * headsz;
  const short* Kh = qkv + (size_t)((1 * 2 + b) * 8 + h) * headsz;
  const short* Vh = qkv + (size_t)((2 * 2 + b) * 8 + h) * headsz;

  __shared__ __align__(16) short k_lds[2][6144];   // [64][96] row-major
  __shared__ __align__(16) short v_lds[2][6144];   // subtiled for tr-read
  __shared__ __align__(16) short p_lds[4][2048];   // per-wave P^T subtiled

  int voff[3];
#pragma unroll
  for (int t = 0; t < 3; ++t) {
    const int c = t * 256 + tid;
    const int kq = c / 48, rem = c - kq * 48;
    const int dhi = rem >> 3, rem2 = rem & 7;
    voff[t] = (kq * 4 + (rem2 >> 1)) * 96 + dhi * 16 + (rem2 & 1) * 8;
  }

  const int qbase = qt * 128 + w * 32;
  bf16x8 qf[2][3];
#pragma unroll
  for (int f = 0; f < 2; ++f)
#pragma unroll
    for (int dk = 0; dk < 3; ++dk) {
      bf16x8 v = *(const bf16x8*)(Qh + (size_t)(qbase + f * 16 + lo) * 96 + dk * 32 + hi * 8);
#pragma unroll
      for (int i = 0; i < 8; ++i) v[i] = f2bs(bs2f(v[i]) * SCALE2);
      qf[f][dk] = v;
    }

  f32x4 o[2][6] = {};
  float mrow[2][4] = {};   // deferred max (log2 units), init 0
  float lpart[2][4] = {};  // per-lane partial row sums
  bool escaped = false;

  auto stage = [&](int t_next, int buf) {
    const short* Kt = Kh + (size_t)t_next * 6144;
    const short* Vt = Vh + (size_t)t_next * 6144;
    char* kd = (char*)k_lds[buf] + w * 1024;
    char* vd = (char*)v_lds[buf] + w * 1024;
#pragma unroll
    for (int t = 0; t < 3; ++t) {
      gload16((const char*)Kt + (t * 256 + tid) * 16, kd + t * 4096);
      gload16(Vt + voff[t], vd + t * 4096);
    }
  };

  stage(0, 0);

  for (int kt = 0; kt < NT; ++kt) {
    const int cur = kt & 1;
    __syncthreads();
    if (kt + 1 < NT) stage(kt + 1, cur ^ 1);

    // ---- QK^T (scores in log2 units) ----
    f32x4 s[2][4] = {};
    const short* kb = k_lds[cur];
#pragma unroll
    for (int dk = 0; dk < 3; ++dk)
#pragma unroll
      for (int c = 0; c < 4; ++c) {
        const bf16x8 kf = *(const bf16x8*)(kb + (c * 16 + lo) * 96 + dk * 32 + hi * 8);
#pragma unroll
        for (int f = 0; f < 2; ++f)
          s[f][c] = MFMA_BF16(qf[f][dk], kf, s[f][c]);
      }

    // ---- softmax (defer-max, log2 domain) ----
    float tm = s[0][0][0];
#pragma unroll
    for (int f = 0; f < 2; ++f)
#pragma unroll
      for (int c = 0; c < 4; ++c)
#pragma unroll
        for (int r = 0; r < 4; ++r) tm = fmaxf(tm, s[f][c][r]);

    if (!__all(tm <= THR2)) {
      escaped = true;
#pragma unroll
      for (int f = 0; f < 2; ++f)
#pragma unroll
        for (int r = 0; r < 4; ++r) {
          float rm = fmaxf(fmaxf(s[f][0][r], s[f][1][r]), fmaxf(s[f][2][r], s[f][3][r]));
          rm = fmaxf(rm, __shfl_xor(rm, 1));
          rm = fmaxf(rm, __shfl_xor(rm, 2));
          rm = fmaxf(rm, __shfl_xor(rm, 4));
          rm = fmaxf(rm, __shfl_xor(rm, 8));
          const float mn = fmaxf(mrow[f][r], rm);
          const float al = EXP2R(mrow[f][r] - mn);
          mrow[f][r] = mn;
          lpart[f][r] *= al;
#pragma unroll
          for (int n = 0; n < 6; ++n) o[f][n][r] *= al;
        }
    }
    if (escaped) {
#pragma unroll
      for (int f = 0; f < 2; ++f)
#pragma unroll
        for (int c = 0; c < 4; ++c)
#pragma unroll
        for (int r = 0; r < 4; ++r) s[f][c][r] = EXP2R(s[f][c][r] - mrow[f][r]);
    } else {
#pragma unroll
      for (int f = 0; f < 2; ++f)
#pragma unroll
        for (int c = 0; c < 4; ++c)
#pragma unroll
        for (int r = 0; r < 4; ++r) s[f][c][r] = EXP2R(s[f][c][r]);
    }

    // ---- lpart accumulate + P^T subtiled store ----
    short* pw = p_lds[w];
#pragma unroll
    for (int f = 0; f < 2; ++f)
#pragma unroll
      for (int c = 0; c < 4; ++c) {
#pragma unroll
        for (int r = 0; r < 4; ++r) lpart[f][r] += s[f][c][r];
        short4 pk;
        pk.x = f2bs(s[f][c][0]);
        pk.y = f2bs(s[f][c][1]);
        pk.z = f2bs(s[f][c][2]);
        pk.w = f2bs(s[f][c][3]);
        *(short4*)(pw + (c * 4 + (lo >> 2)) * 128 + f * 64 + (lo & 3) * 16 + hi * 4) = pk;
      }

    // ---- PV: tr-read V (B-op) and P^T (A-op), MFMA ----
    const unsigned vb = ldsoff(v_lds[cur]) + (unsigned)(hi * 1536 + lo * 2);
    const unsigned pb = ldsoff(p_lds[w]) + (unsigned)(hi * 512 + lo * 2);

    {  // kk = 0
      bf16x4 va[6], vbh[6], pa0[2], pa1[2];
      TRD(va[0], vb, 0);     TRD(vbh[0], vb, 768);
      TRD(va[1], vb, 128);   TRD(vbh[1], vb, 896);
      TRD(va[2], vb, 256);   TRD(vbh[2], vb, 1024);
      TRD(va[3], vb, 384);   TRD(vbh[3], vb, 1152);
      TRD(va[4], vb, 512);   TRD(vbh[4], vb, 1280);
      TRD(va[5], vb, 640);   TRD(vbh[5], vb, 1408);
      TRD(pa0[0], pb, 0);    TRD(pa1[0], pb, 256);
      TRD(pa0[1], pb, 128);  TRD(pa1[1], pb, 384);
      asm volatile("s_waitcnt lgkmcnt(0)" ::: "memory");
      __builtin_amdgcn_sched_barrier(0);
      __builtin_amdgcn_s_setprio(1);
#pragma unroll
      for (int f = 0; f < 2; ++f) {
        const bf16x8 pf = __builtin_shufflevector(pa0[f], pa1[f], 0, 1, 2, 3, 4, 5, 6, 7);
#pragma unroll
        for (int n = 0; n < 6; ++n) {
          const bf16x8 vf = __builtin_shufflevector(va[n], vbh[n], 0, 1, 2, 3, 4, 5, 6, 7);
          o[f][n] = MFMA_BF16(pf, vf, o[f][n]);
        }
      }
      __builtin_amdgcn_s_setprio(0);
    }
    {  // kk = 1 (V +6144 bytes, P +2048 bytes)
      bf16x4 va[6], vbh[6], pa0[2], pa1[2];
      TRD(va[0], vb, 6144);  TRD(vbh[0], vb, 6912);
      TRD(va[1], vb, 6272);  TRD(vbh[1], vb, 7040);
      TRD(va[2], vb, 6400);  TRD(vbh[2], vb, 7168);
      TRD(va[3], vb, 6528);  TRD(vbh[3], vb, 7296);
      TRD(va[4], vb, 6656);  TRD(vbh[4], vb, 7424);
      TRD(va[5], vb, 6784);  TRD(vbh[5], vb, 7552);
      TRD(pa0[0], pb, 2048); TRD(pa1[0], pb, 2304);
      TRD(pa0[1], pb, 2176); TRD(pa1[1], pb, 2432);
      asm volatile("s_waitcnt lgkmcnt(0)" ::: "memory");
      __builtin_amdgcn_sched_barrier(0);
      __builtin_amdgcn_s_setprio(1);
#pragma unroll
      for (int f = 0; f < 2; ++f) {
        const bf16x8 pf = __builtin_shufflevector(pa0[f], pa1[f], 0, 1, 2, 3, 4, 5, 6, 7);
#pragma unroll
        for (int n = 0; n < 6; ++n) {
          const bf16x8 vf = __builtin_shufflevector(va[n], vbh[n], 0, 1, 2, 3, 4, 5, 6, 7);
          o[f][n] = MFMA_BF16(pf, vf, o[f][n]);
        }
      }
      __builtin_amdgcn_s_setprio(0);
    }
  }

  // ---- epilogue ----
  float inv[2][4];
#pragma unroll
  for (int f = 0; f < 2; ++f)
#pragma unroll
    for (int r = 0; r < 4; ++r) {
      float l = lpart[f][r];
      l += __shfl_xor(l, 1);
      l += __shfl_xor(l, 2);
      l += __shfl_xor(l, 4);
      l += __shfl_xor(l, 8);
      inv[f][r] = 1.f / l;
    }
#pragma unroll
  for (int f = 0; f < 2; ++f)
#pragma unroll
    for (int n = 0; n < 6; ++n)
#pragma unroll
      for (int r = 0; r < 4; ++r) {
        const int q = qbase + f * 16 + hi * 4 + r;
        out[((size_t)(b * SEQ + q)) * 768 + h * 96 + n * 16 + lo] = f2bs(o[f][n][r] * inv[f][r]);
      }
}

// ---------------------------------------------------------------------------
// LN(a + r) with bf16 r.  MODE 0 (LN1): a fp32, write bf16 only.
// MODE 1 (LN2): a bf16, write fp32 only.
// ---------------------------------------------------------------------------
template <int MODE>
__global__ __launch_bounds__(192) void ln_residual(const void* __restrict__ xa_,
                                                   const short* __restrict__ xr,
                                                   const float* __restrict__ g,
                                                   const float* __restrict__ be,
                                                   float* __restrict__ outf,
                                                   short* __restrict__ outb) {
  const int row = blockIdx.x, t = threadIdx.x;
  const size_t base = (size_t)row * 768 + t * 4;
  float a0, a1, a2, a3;
  if constexpr (MODE == 0) {
    const float4 a = *(const float4*)((const float*)xa_ + base);
    a0 = a.x; a1 = a.y; a2 = a.z; a3 = a.w;
  } else {
    const short4 a = *(const short4*)((const short*)xa_ + base);
    a0 = bs2f(a.x); a1 = bs2f(a.y); a2 = bs2f(a.z); a3 = bs2f(a.w);
  }
  const short4 bl = *(const short4*)(xr + base);
  const float v0 = a0 + bs2f(bl.x), v1 = a1 + bs2f(bl.y);
  const float v2 = a2 + bs2f(bl.z), v3 = a3 + bs2f(bl.w);
  float s = v0 + v1 + v2 + v3;
  float q = v0 * v0 + v1 * v1 + v2 * v2 + v3 * v3;
#pragma unroll
  for (int m = 32; m; m >>= 1) {
    s += __shfl_xor(s, m);
    q += __shfl_xor(q, m);
  }
  __shared__ float red[2][3];
  const int w = t >> 6;
  if ((t & 63) == 0) { red[0][w] = s; red[1][w] = q; }
  __syncthreads();
  s = red[0][0] + red[0][1] + red[0][2];
  q = red[1][0] + red[1][1] + red[1][2];
  const float mu = s * (1.f / 768.f);
  const float var = q * (1.f / 768.f) - mu * mu;
  const float rstd = rsqrtf(var + 1e-5f);
  const int c = t * 4;
  const float4 gg = *(const float4*)(g + c);
  const float4 bb = *(const float4*)(be + c);
  const float y0 = (v0 - mu) * rstd * gg.x + bb.x;
  const float y1 = (v1 - mu) * rstd * gg.y + bb.y;
  const float y2 = (v2 - mu) * rstd * gg.z + bb.z;
  const float y3 = (v3 - mu) * rstd * gg.w + bb.w;
  if constexpr (MODE == 0) {
    short4 ob;
    ob.x = f2bs(y0); ob.y = f2bs(y1); ob.z = f2bs(y2); ob.w = f2bs(y3);
    *(short4*)(outb + base) = ob;
  } else {
    float4 ov = {y0, y1, y2, y3};
    *(float4*)(outf + base) = ov;
  }
}

// ---------------------------------------------------------------------------
extern "C" void kernel_launch(void* const* d_in, const int* in_sizes, int n_in,
                              void* d_out, int out_size, void* d_ws, size_t ws_size,
                              hipStream_t stream) {
  const float* x     = (const float*)d_in[0];
  const float* w_qkv = (const float*)d_in[1];
  const float* b_qkv = (const float*)d_in[2];
  const float* w_out = (const float*)d_in[3];
  const float* b_out = (const float*)d_in[4];
  const float* w_ff1 = (const float*)d_in[5];
  const float* b_ff1 = (const float*)d_in[6];
  const float* w_ff2 = (const float*)d_in[7];
  const float* b_ff2 = (const float*)d_in[8];
  const float* g1  = (const float*)d_in[9];
  const float* be1 = (const float*)d_in[10];
  const float* g2  = (const float*)d_in[11];
  const float* be2 = (const float*)d_in[12];

  char* ws = (char*)d_ws;
  size_t off = 0;
  auto take = [&](size_t bytes) {
    char* p = ws + off;
    off += (bytes + 255) & ~(size_t)255;
    return p;
  };
  short* wqkv_t = (short*)take((size_t)2304 * 768 * 2);
  short* wout_t = (short*)take((size_t)768 * 768 * 2);
  short* wff1_t = (short*)take((size_t)3072 * 768 * 2);
  short* wff2_t = (short*)take((size_t)768 * 3072 * 2);
  short* xb     = (short*)take((size_t)8192 * 768 * 2);
  short* qkv    = (short*)take((size_t)3 * 2 * 8 * 4096 * 96 * 2);
  short* ao     = (short*)take((size_t)8192 * 768 * 2);
  short* x1b    = (short*)take((size_t)8192 * 768 * 2);
  if (ws_size < off) return;

  short* proj = qkv;          // alias: qkv dead after attention (bf16)
  short* hbuf = xb;           // alias: xb+qkv region
  short* ff2o = ao;           // alias: ao region (bf16)

  cast_bf16<<<dim3(6144), dim3(256), 0, stream>>>(x, xb, 8192 * 768 / 4);
  transpose_cast<<<dim3(2304 / 32, 768 / 32), dim3(256), 0, stream>>>(w_qkv, wqkv_t, 768, 2304);
  transpose_cast<<<dim3(768 / 32, 768 / 32), dim3(256), 0, stream>>>(w_out, wout_t, 768, 768);
  transpose_cast<<<dim3(3072 / 32, 768 / 32), dim3(256), 0, stream>>>(w_ff1, wff1_t, 768, 3072);
  transpose_cast<<<dim3(768 / 32, 3072 / 32), dim3(256), 0, stream>>>(w_ff2, wff2_t, 3072, 768);

  gemm_bt<0><<<dim3(2304 / 128, 8192 / 128), dim3(256), 0, stream>>>(xb, wqkv_t, b_qkv, qkv, 2304, 768);

  attn_fwd<<<dim3(32, 8, 2), dim3(256), 0, stream>>>(qkv, ao);

  gemm_bt<1><<<dim3(768 / 128, 8192 / 128), dim3(256), 0, stream>>>(ao, wout_t, b_out, proj, 768, 768);

  ln_residual<0><<<dim3(8192), dim3(192), 0, stream>>>(x, proj, g1, be1, nullptr, x1b);

  gemm_bt<2><<<dim3(3072 / 128, 8192 / 128), dim3(256), 0, stream>>>(x1b, wff1_t, b_ff1, hbuf, 3072, 768);

  gemm_bt<1><<<dim3(768 / 128, 8192 / 128), dim3(256), 0, stream>>>(hbuf, wff2_t, b_ff2, ff2o, 768, 3072);

  ln_residual<1><<<dim3(8192), dim3(192), 0, stream>>>(x1b, ff2o, g2, be2, (float*)d_out, nullptr);
}